// Round 1
// baseline (2410.267 us; speedup 1.0000x reference)
//
#include <hip/hip_runtime.h>
#include <math.h>

#define BN   8
#define NN   2048
#define NP1  2049
#define DD   256
#define NITER 20

// ws layout (floats): a[BN*NP1] | b[BN*NP1] | sums[41][BN]

__global__ void init_kernel(float* __restrict__ ws) {
    float* bvec = ws + BN * NP1;
    float* sums = ws + 2 * BN * NP1;
    int tid = blockIdx.x * blockDim.x + threadIdx.x;
    int stride = gridDim.x * blockDim.x;
    for (int i = tid; i < BN * NP1; i += stride) bvec[i] = 1.0f;       // v0 = 0 -> b = 1
    for (int i = tid; i < 41 * BN; i += stride) sums[i] = (i < BN) ? (float)NN : 0.0f;
}

// K = exp(F^T F / 16), diag = 0, written into out's top-left NxN (stride NP1).
// Symmetric: compute only tj >= ti tiles, mirror-write.
__global__ __launch_bounds__(256) void build_k_kernel(const float* __restrict__ F,
                                                      float* __restrict__ out) {
    int ti = blockIdx.x, tj = blockIdx.y, bb = blockIdx.z;
    if (tj < ti) return;
    __shared__ float As[32][64];
    __shared__ float Bs[32][64];
    int t  = threadIdx.x;
    int tx = t & 15, ty = t >> 4;
    float acc[4][4] = {};
    const float* Fb = F + (size_t)bb * DD * NN;
    int i0 = ti * 64, j0 = tj * 64;
    for (int k0 = 0; k0 < DD; k0 += 32) {
#pragma unroll
        for (int v = 0; v < 2; v++) {
            int f = t + 256 * v;
            int row = f >> 4, c4 = (f & 15) * 4;
            *(float4*)&As[row][c4] = *(const float4*)&Fb[(size_t)(k0 + row) * NN + i0 + c4];
            *(float4*)&Bs[row][c4] = *(const float4*)&Fb[(size_t)(k0 + row) * NN + j0 + c4];
        }
        __syncthreads();
#pragma unroll
        for (int k = 0; k < 32; k++) {
            float4 av = *(float4*)&As[k][ty * 4];
            float4 bv = *(float4*)&Bs[k][tx * 4];
            float ar[4] = {av.x, av.y, av.z, av.w};
            float br[4] = {bv.x, bv.y, bv.z, bv.w};
#pragma unroll
            for (int r = 0; r < 4; r++)
#pragma unroll
                for (int c = 0; c < 4; c++)
                    acc[r][c] = fmaf(ar[r], br[c], acc[r][c]);
        }
        __syncthreads();
    }
    float* outb = out + (size_t)bb * NP1 * NP1;
#pragma unroll
    for (int r = 0; r < 4; r++) {
        int i = i0 + ty * 4 + r;
#pragma unroll
        for (int c = 0; c < 4; c++) {
            int j = j0 + tx * 4 + c;
            float Kv = (i == j) ? 0.0f : __expf(acc[r][c] * 0.0625f);  // scale = 1/sqrt(256)
            outb[(size_t)i * NP1 + j] = Kv;
            if (tj > ti) outb[(size_t)j * NP1 + i] = Kv;
        }
    }
}

// One Sinkhorn half-step: xout_i = (1/4096) / (sum_j K[i,j]*xin_j + E*xin_N), i < N
//                         xout_N = 0.5 / (E * (sum_in + xin_N))
// Accumulates sum_{i<N} xout_i into sum_out[batch] via one atomic per block.
__global__ __launch_bounds__(256) void sink_pass_kernel(const float* __restrict__ K,
                                                        const float* __restrict__ xin,
                                                        float* __restrict__ xout,
                                                        const float* __restrict__ sum_in,
                                                        float* __restrict__ sum_out,
                                                        const float* __restrict__ alpha) {
    int bb = blockIdx.y;
    int i0 = blockIdx.x * 16;
    __shared__ float xs[NN];
    __shared__ float rowa[16];
    const float* xinb = xin + bb * NP1;
    int t = threadIdx.x;
    for (int j = t; j < NN; j += 256) xs[j] = xinb[j];
    __syncthreads();
    float E  = __expf(alpha[0]);
    float xN = xinb[NN];
    int wave = t >> 6, lane = t & 63;
    const float* Kb = K + (size_t)bb * NP1 * NP1;
    for (int r = wave; r < 16; r += 4) {
        int i = i0 + r;
        const float* row = Kb + (size_t)i * NP1;
        float acc = 0.f;
        for (int j = lane; j < NN; j += 64) acc = fmaf(row[j], xs[j], acc);
#pragma unroll
        for (int off = 32; off >= 1; off >>= 1) acc += __shfl_xor(acc, off);
        if (lane == 0) {
            float val = (1.0f / 4096.0f) / (acc + E * xN);
            xout[bb * NP1 + i] = val;
            rowa[r] = val;
        }
    }
    __syncthreads();
    if (t == 0) {
        float s = 0.f;
#pragma unroll
        for (int r = 0; r < 16; r++) s += rowa[r];
        atomicAdd(sum_out + bb, s);
        if (blockIdx.x == 0) {
            float sin = sum_in[bb];
            xout[bb * NP1 + NN] = 0.5f / (E * (sin + xN));
        }
    }
}

// out[i,j] = K*a_i*b_j*4096*cost (i,j<N, in-place on K), bins use E=exp(alpha).
__global__ __launch_bounds__(256) void final_kernel(float* __restrict__ out,
                                                    const float* __restrict__ avec,
                                                    const float* __restrict__ bvec,
                                                    const float* __restrict__ pos,
                                                    const float* __restrict__ alpha) {
    int bb = blockIdx.y;
    int i0 = blockIdx.x * 16;
    __shared__ float as_[16], ys[16], xs2[16];
    int t = threadIdx.x;
    if (t < 16) {
        int i = i0 + t;
        as_[t] = (i < NP1) ? avec[bb * NP1 + i] : 0.f;
        if (i < NN) {
            ys[t]  = pos[((size_t)bb * NN + i) * 2 + 0];
            xs2[t] = pos[((size_t)bb * NN + i) * 2 + 1];
        } else {
            ys[t] = 1e9f; xs2[t] = 1e9f;
        }
    }
    __syncthreads();
    float E = __expf(alpha[0]);
    float* outb = out + (size_t)bb * NP1 * NP1;
    for (int j = t; j < NP1; j += 256) {
        float bj = bvec[bb * NP1 + j];
        bool jin = (j < NN);
        float yj = 0.f, xj = 0.f;
        if (jin) {
            yj = pos[((size_t)bb * NN + j) * 2 + 0];
            xj = pos[((size_t)bb * NN + j) * 2 + 1];
        }
#pragma unroll 1
        for (int r = 0; r < 16; r++) {
            int i = i0 + r;
            if (i >= NP1) break;
            size_t idx = (size_t)i * NP1 + j;
            float v;
            if (i < NN && jin) {
                float Kv = outb[idx];
                bool c = (fabsf(ys[r] - yj) <= 0.1f) && (fabsf(xs2[r] - xj) <= 0.1f);
                v = c ? Kv * as_[r] * bj * 4096.0f : 0.0f;
            } else {
                v = E * as_[r] * bj * 4096.0f;
            }
            outb[idx] = v;
        }
    }
}

extern "C" void kernel_launch(void* const* d_in, const int* in_sizes, int n_in,
                              void* d_out, int out_size, void* d_ws, size_t ws_size,
                              hipStream_t stream) {
    const float* F     = (const float*)d_in[0];  // (B, D, N)
    const float* pos   = (const float*)d_in[1];  // (B, N, 2)
    const float* alpha = (const float*)d_in[3];  // (1,)
    float* out = (float*)d_out;
    float* ws  = (float*)d_ws;

    float* avec = ws;
    float* bvec = ws + BN * NP1;
    float* sums = ws + 2 * BN * NP1;

    hipLaunchKernelGGL(init_kernel, dim3(64), dim3(256), 0, stream, ws);
    hipLaunchKernelGGL(build_k_kernel, dim3(32, 32, BN), dim3(256), 0, stream, F, out);

    const float* xin = bvec;
    float* xout = avec;
    for (int p = 1; p <= 2 * NITER; p++) {
        hipLaunchKernelGGL(sink_pass_kernel, dim3(NN / 16, BN), dim3(256), 0, stream,
                           out, xin, xout, sums + (p - 1) * BN, sums + p * BN, alpha);
        float* tmp = (float*)xin;
        xin  = xout;
        xout = tmp;
    }
    // after 40 passes: avec holds exp(u20), bvec holds exp(v20)
    hipLaunchKernelGGL(final_kernel, dim3((NP1 + 15) / 16, BN), dim3(256), 0, stream,
                       out, avec, bvec, pos, alpha);
}

// Round 2
// 1144.131 us; speedup vs baseline: 2.1066x; 2.1066x over previous
//
#include <hip/hip_runtime.h>
#include <hip/hip_fp16.h>
#include <math.h>

#define BN    8
#define NN    2048
#define NP1   2049
#define VSTR  2056   // padded a/b vector stride (floats) so batch rows stay 16B-aligned
#define DD    256
#define NITER 20

// ws layout (floats): a[BN*VSTR] | b[BN*VSTR] | sums[41*BN] | (align16) Kh[BN*NN*NN] (half)

__global__ void init_kernel(float* __restrict__ bvec, int nb, float* __restrict__ sums) {
    int tid = blockIdx.x * blockDim.x + threadIdx.x;
    int stride = gridDim.x * blockDim.x;
    for (int i = tid; i < nb; i += stride) bvec[i] = 1.0f;            // v0 = 0 -> b = 1
    for (int i = tid; i < 41 * BN; i += stride) sums[i] = (i < BN) ? (float)NN : 0.0f;
}

// K = exp(F^T F / 16), diag = 0. F16 variant writes half K (stride NN) to Kh;
// fp32 variant writes into out's top-left NxN (stride NP1). Symmetric: tj>=ti only.
template <bool F16>
__global__ __launch_bounds__(256) void build_k_kernel(const float* __restrict__ F,
                                                      float* __restrict__ out,
                                                      __half* __restrict__ Kh) {
    int ti = blockIdx.x, tj = blockIdx.y, bb = blockIdx.z;
    if (tj < ti) return;
    __shared__ float As[32][64];
    __shared__ float Bs[32][64];
    int t  = threadIdx.x;
    int tx = t & 15, ty = t >> 4;
    float acc[4][4] = {};
    const float* Fb = F + (size_t)bb * DD * NN;
    int i0 = ti * 64, j0 = tj * 64;
    for (int k0 = 0; k0 < DD; k0 += 32) {
#pragma unroll
        for (int v = 0; v < 2; v++) {
            int f = t + 256 * v;
            int row = f >> 4, c4 = (f & 15) * 4;
            *(float4*)&As[row][c4] = *(const float4*)&Fb[(size_t)(k0 + row) * NN + i0 + c4];
            *(float4*)&Bs[row][c4] = *(const float4*)&Fb[(size_t)(k0 + row) * NN + j0 + c4];
        }
        __syncthreads();
#pragma unroll
        for (int k = 0; k < 32; k++) {
            float4 av = *(float4*)&As[k][ty * 4];
            float4 bv = *(float4*)&Bs[k][tx * 4];
            float ar[4] = {av.x, av.y, av.z, av.w};
            float br[4] = {bv.x, bv.y, bv.z, bv.w};
#pragma unroll
            for (int r = 0; r < 4; r++)
#pragma unroll
                for (int c = 0; c < 4; c++)
                    acc[r][c] = fmaf(ar[r], br[c], acc[r][c]);
        }
        __syncthreads();
    }
#pragma unroll
    for (int r = 0; r < 4; r++) {
        int i = i0 + ty * 4 + r;
#pragma unroll
        for (int c = 0; c < 4; c++) {
            int j = j0 + tx * 4 + c;
            float Kv = (i == j) ? 0.0f : __expf(acc[r][c] * 0.0625f);  // 1/sqrt(256)
            if constexpr (F16) {
                __half* Khb = Kh + (size_t)bb * NN * NN;
                __half h = __float2half_rn(Kv);
                Khb[(size_t)i * NN + j] = h;
                if (tj > ti) Khb[(size_t)j * NN + i] = h;
            } else {
                float* outb = out + (size_t)bb * NP1 * NP1;
                outb[(size_t)i * NP1 + j] = Kv;
                if (tj > ti) outb[(size_t)j * NP1 + i] = Kv;
            }
        }
    }
}

// fp16-K Sinkhorn half-step. x kept in registers (32 floats/lane), K read as int4
// (8 halves = 16B/lane). xout_i = (1/4096)/(sum_j K_ij x_j + E*x_N); bin via sums.
__global__ __launch_bounds__(256) void sink_pass_f16(const __half* __restrict__ K,
                                                     const float* __restrict__ xin,
                                                     float* __restrict__ xout,
                                                     const float* __restrict__ sum_in,
                                                     float* __restrict__ sum_out,
                                                     const float* __restrict__ alpha) {
    int bb = blockIdx.y;
    int i0 = blockIdx.x * 16;
    const float* xinb = xin + (size_t)bb * VSTR;
    int t = threadIdx.x, wave = t >> 6, lane = t & 63;
    // per-lane x chunks: chunk c = lane + 64k holds x[8c .. 8c+7]
    float xr[4][8];
#pragma unroll
    for (int k = 0; k < 4; k++) {
        const float4* p = (const float4*)(xinb + (size_t)(lane + 64 * k) * 8);
        float4 a = p[0], b = p[1];
        xr[k][0] = a.x; xr[k][1] = a.y; xr[k][2] = a.z; xr[k][3] = a.w;
        xr[k][4] = b.x; xr[k][5] = b.y; xr[k][6] = b.z; xr[k][7] = b.w;
    }
    float E  = __expf(alpha[0]);
    float xN = xinb[NN];
    __shared__ float rowa[16];
    const __half* Kb = K + (size_t)bb * NN * NN;
    for (int r = wave; r < 16; r += 4) {
        int i = i0 + r;
        const int4* row = (const int4*)(Kb + (size_t)i * NN);
        float acc = 0.f;
#pragma unroll
        for (int k = 0; k < 4; k++) {
            int4 pv = row[lane + 64 * k];
            const __half* hp = (const __half*)&pv;
#pragma unroll
            for (int q = 0; q < 8; q++)
                acc = fmaf(__half2float(hp[q]), xr[k][q], acc);
        }
#pragma unroll
        for (int off = 32; off >= 1; off >>= 1) acc += __shfl_xor(acc, off);
        if (lane == 0) {
            float val = (1.0f / 4096.0f) / (acc + E * xN);
            xout[(size_t)bb * VSTR + i] = val;
            rowa[r] = val;
        }
    }
    __syncthreads();
    if (t == 0) {
        float s = 0.f;
#pragma unroll
        for (int r = 0; r < 16; r++) s += rowa[r];
        atomicAdd(sum_out + bb, s);
        if (blockIdx.x == 0) {
            float sin = sum_in[bb];
            xout[(size_t)bb * VSTR + NN] = 0.5f / (E * (sin + xN));
        }
    }
}

// fp32 fallback pass (K in d_out, stride NP1).
__global__ __launch_bounds__(256) void sink_pass_f32(const float* __restrict__ K,
                                                     const float* __restrict__ xin,
                                                     float* __restrict__ xout,
                                                     const float* __restrict__ sum_in,
                                                     float* __restrict__ sum_out,
                                                     const float* __restrict__ alpha) {
    int bb = blockIdx.y;
    int i0 = blockIdx.x * 16;
    __shared__ float xs[NN];
    __shared__ float rowa[16];
    const float* xinb = xin + (size_t)bb * VSTR;
    int t = threadIdx.x;
    for (int j = t; j < NN; j += 256) xs[j] = xinb[j];
    __syncthreads();
    float E  = __expf(alpha[0]);
    float xN = xinb[NN];
    int wave = t >> 6, lane = t & 63;
    const float* Kb = K + (size_t)bb * NP1 * NP1;
    for (int r = wave; r < 16; r += 4) {
        int i = i0 + r;
        const float* row = Kb + (size_t)i * NP1;
        float acc = 0.f;
        for (int j = lane; j < NN; j += 64) acc = fmaf(row[j], xs[j], acc);
#pragma unroll
        for (int off = 32; off >= 1; off >>= 1) acc += __shfl_xor(acc, off);
        if (lane == 0) {
            float val = (1.0f / 4096.0f) / (acc + E * xN);
            xout[(size_t)bb * VSTR + i] = val;
            rowa[r] = val;
        }
    }
    __syncthreads();
    if (t == 0) {
        float s = 0.f;
#pragma unroll
        for (int r = 0; r < 16; r++) s += rowa[r];
        atomicAdd(sum_out + bb, s);
        if (blockIdx.x == 0) {
            float sin = sum_in[bb];
            xout[(size_t)bb * VSTR + NN] = 0.5f / (E * (sin + xN));
        }
    }
}

// out[i,j] = K*a_i*b_j*4096*cost (i,j<N), bins use E. F16: K from Kh; else in-place on out.
template <bool F16>
__global__ __launch_bounds__(256) void final_kernel(float* __restrict__ out,
                                                    const __half* __restrict__ Kh,
                                                    const float* __restrict__ avec,
                                                    const float* __restrict__ bvec,
                                                    const float* __restrict__ pos,
                                                    const float* __restrict__ alpha) {
    int bb = blockIdx.y;
    int i0 = blockIdx.x * 16;
    __shared__ float as_[16], ys[16], xs2[16];
    int t = threadIdx.x;
    if (t < 16) {
        int i = i0 + t;
        as_[t] = (i < NP1) ? avec[(size_t)bb * VSTR + i] : 0.f;
        if (i < NN) {
            ys[t]  = pos[((size_t)bb * NN + i) * 2 + 0];
            xs2[t] = pos[((size_t)bb * NN + i) * 2 + 1];
        } else {
            ys[t] = 1e9f; xs2[t] = 1e9f;
        }
    }
    __syncthreads();
    float E = __expf(alpha[0]);
    float* outb = out + (size_t)bb * NP1 * NP1;
    const __half* Khb = Kh + (size_t)bb * NN * NN;
    for (int j = t; j < NP1; j += 256) {
        float bj = bvec[(size_t)bb * VSTR + j];
        bool jin = (j < NN);
        float yj = 0.f, xj = 0.f;
        if (jin) {
            yj = pos[((size_t)bb * NN + j) * 2 + 0];
            xj = pos[((size_t)bb * NN + j) * 2 + 1];
        }
#pragma unroll 1
        for (int r = 0; r < 16; r++) {
            int i = i0 + r;
            if (i >= NP1) break;
            size_t idx = (size_t)i * NP1 + j;
            float v;
            if (i < NN && jin) {
                float Kv = F16 ? __half2float(Khb[(size_t)i * NN + j]) : outb[idx];
                bool c = (fabsf(ys[r] - yj) <= 0.1f) && (fabsf(xs2[r] - xj) <= 0.1f);
                v = c ? Kv * as_[r] * bj * 4096.0f : 0.0f;
            } else {
                v = E * as_[r] * bj * 4096.0f;
            }
            outb[idx] = v;
        }
    }
}

extern "C" void kernel_launch(void* const* d_in, const int* in_sizes, int n_in,
                              void* d_out, int out_size, void* d_ws, size_t ws_size,
                              hipStream_t stream) {
    const float* F     = (const float*)d_in[0];  // (B, D, N)
    const float* pos   = (const float*)d_in[1];  // (B, N, 2)
    const float* alpha = (const float*)d_in[3];  // (1,)
    float* out = (float*)d_out;
    float* ws  = (float*)d_ws;

    float* avec = ws;
    float* bvec = ws + BN * VSTR;
    float* sums = ws + 2 * BN * VSTR;                 // 41*BN floats
    __half* Kh  = (__half*)(sums + 41 * BN);          // offset 132896 B, 16B-aligned

    size_t need = (size_t)(2 * BN * VSTR + 41 * BN) * 4 + (size_t)BN * NN * NN * 2;
    bool f16 = (ws_size >= need);

    hipLaunchKernelGGL(init_kernel, dim3(64), dim3(256), 0, stream, bvec, BN * VSTR, sums);

    if (f16) {
        hipLaunchKernelGGL((build_k_kernel<true>), dim3(32, 32, BN), dim3(256), 0, stream,
                           F, out, Kh);
        const float* xin = bvec;
        float* xout = avec;
        for (int p = 1; p <= 2 * NITER; p++) {
            hipLaunchKernelGGL(sink_pass_f16, dim3(NN / 16, BN), dim3(256), 0, stream,
                               Kh, xin, xout, sums + (p - 1) * BN, sums + p * BN, alpha);
            float* tmp = (float*)xin; xin = xout; xout = tmp;
        }
        hipLaunchKernelGGL((final_kernel<true>), dim3((NP1 + 15) / 16, BN), dim3(256), 0,
                           stream, out, Kh, avec, bvec, pos, alpha);
    } else {
        hipLaunchKernelGGL((build_k_kernel<false>), dim3(32, 32, BN), dim3(256), 0, stream,
                           F, out, Kh);
        const float* xin = bvec;
        float* xout = avec;
        for (int p = 1; p <= 2 * NITER; p++) {
            hipLaunchKernelGGL(sink_pass_f32, dim3(NN / 16, BN), dim3(256), 0, stream,
                               out, xin, xout, sums + (p - 1) * BN, sums + p * BN, alpha);
            float* tmp = (float*)xin; xin = xout; xout = tmp;
        }
        hipLaunchKernelGGL((final_kernel<false>), dim3((NP1 + 15) / 16, BN), dim3(256), 0,
                           stream, out, Kh, avec, bvec, pos, alpha);
    }
}